// Round 1
// baseline (469.827 us; speedup 1.0000x reference)
//
#include <hip/hip_runtime.h>

// Problem constants (from reference): B=64, T=2048, D=64, V=100000
#define BB 64
#define TT 2048
#define DD 64
#define BT (BB * TT)                 // 131072
#define OFF_F 0                      // features [B,T,256]
#define OFF_T (BT * 256)             // times    [B,T]        = 33554432
#define OFF_D (OFF_T + BT)           // delta    [B,T,256]    = 33685504
#define OFF_M (OFF_D + BT * 256)     // mask     [B,T,256]    = 67239936

// padded LDS index: insert 1 gap every 32 elems -> per-lane chunk reads are
// 2-way bank aliased (free on gfx950) instead of 64-way conflicts
__device__ __forceinline__ int pidx(int i) { return i + (i >> 5); }

// ---------------------------------------------------------------------------
// Phase 1: beta linear recurrence, one block per batch row, wave f scans
// feature f. beta[i] = a_i*beta[i-1] + c_i,  a_i = m_{i-1}*pad_i (0/1),
// c_i = dt_i*pad_i. Chunked serial scan + wave-level affine-map scan.
// All values are exact small integers in fp32 -> bitwise == reference scan.
// ---------------------------------------------------------------------------
__global__ __launch_bounds__(256) void beta_scan_kernel(
    const int* __restrict__ cat1, const int* __restrict__ cat2,
    const float* __restrict__ num1, const float* __restrict__ num2,
    const float* __restrict__ times, float* __restrict__ beta_ws)
{
    __shared__ float s_t[2112];
    __shared__ float s_f[4][2112];
    const int b   = blockIdx.x;
    const int tid = threadIdx.x;

    for (int i = tid; i < TT; i += 256) {
        int g = b * TT + i;
        s_t[pidx(i)]    = times[g];
        s_f[0][pidx(i)] = (float)cat1[g];   // values < 2^24: float cast exact
        s_f[1][pidx(i)] = (float)cat2[g];
        s_f[2][pidx(i)] = num1[g];
        s_f[3][pidx(i)] = num2[g];
    }
    __syncthreads();

    const int f    = tid >> 6;
    const int lane = tid & 63;
    const int lo   = lane * 32;

    // pass 1: compose the 32 affine steps of this lane's chunk
    float A = 1.f, C = 0.f;
    #pragma unroll
    for (int k = 0; k < 32; ++k) {
        int i = lo + k;
        float a, c;
        if (i == 0) { a = 0.f; c = 0.f; }   // beta[0] = 0
        else {
            float ti  = s_t[pidx(i)];
            float tp  = s_t[pidx(i - 1)];
            float fv  = s_f[f][pidx(i - 1)];
            float pad = (ti != -1.f) ? 1.f : 0.f;
            float m   = (fv != -1.f && fv != 0.f) ? 1.f : 0.f;
            a = m * pad;
            c = (ti - tp) * pad;
        }
        C = a * C + c;
        A = A * a;
    }
    // inclusive wave scan of affine maps (compose: self after prev)
    for (int d = 1; d < 64; d <<= 1) {
        float Ap = __shfl_up(A, d);
        float Cp = __shfl_up(C, d);
        if (lane >= d) { C = A * Cp + C; A = A * Ap; }
    }
    // beta entering this lane's chunk = inclusive C of lane-1 (applied to 0)
    float beta = __shfl_up(C, 1);
    if (lane == 0) beta = 0.f;

    // pass 2: replay serially with the true incoming beta, write out
    float* out = beta_ws + (f * BB + b) * TT;
    #pragma unroll
    for (int k = 0; k < 32; ++k) {
        int i = lo + k;
        float a, c;
        if (i == 0) { a = 0.f; c = 0.f; }
        else {
            float ti  = s_t[pidx(i)];
            float tp  = s_t[pidx(i - 1)];
            float fv  = s_f[f][pidx(i - 1)];
            float pad = (ti != -1.f) ? 1.f : 0.f;
            float m   = (fv != -1.f && fv != 0.f) ? 1.f : 0.f;
            a = m * pad;
            c = (ti - tp) * pad;
        }
        beta = a * beta + c;
        out[i] = beta;
    }
}

// ---------------------------------------------------------------------------
// Phase 2: expansion. One thread per float4 chunk of the wide outputs,
// f-major mapping -> every wave is branch-uniform (f constant per wave).
// u = f * (BT*16) + bt * 16 + c,  c in [0,16) selects float4 within 64 floats.
// Each thread: 1 gather (or FMA) + 3 coalesced float4 stores.
// ---------------------------------------------------------------------------
__global__ __launch_bounds__(256) void expand_kernel(
    const int* __restrict__ cat1, const int* __restrict__ cat2,
    const float* __restrict__ num1, const float* __restrict__ num2,
    const float* __restrict__ times,
    const float* __restrict__ E1, const float* __restrict__ E2,
    const float* __restrict__ w1, const float* __restrict__ b1,
    const float* __restrict__ w2, const float* __restrict__ b2,
    const float* __restrict__ beta_ws, float* __restrict__ out)
{
    const int u  = blockIdx.x * 256 + threadIdx.x;  // [0, 4*BT*16) = [0, 2^23)
    const int f  = u >> 21;                          // BT*16 = 2^21
    const int r  = u & ((1 << 21) - 1);
    const int bt = r >> 4;
    const int c  = r & 15;

    float4 v;
    float  mval;
    if (f == 0) {
        int idx = cat1[bt];
        v = ((const float4*)(E1 + (size_t)idx * DD))[c];
        mval = (idx != -1 && idx != 0) ? 1.f : 0.f;
    } else if (f == 1) {
        int idx = cat2[bt];
        v = ((const float4*)(E2 + (size_t)idx * DD))[c];
        mval = (idx != -1 && idx != 0) ? 1.f : 0.f;
    } else if (f == 2) {
        float x   = num1[bt];
        float4 w  = ((const float4*)w1)[c];
        float4 bb = ((const float4*)b1)[c];
        v = make_float4(x * w.x + bb.x, x * w.y + bb.y,
                        x * w.z + bb.z, x * w.w + bb.w);
        mval = (x != -1.f && x != 0.f) ? 1.f : 0.f;
    } else {
        float x   = num2[bt];
        float4 w  = ((const float4*)w2)[c];
        float4 bb = ((const float4*)b2)[c];
        v = make_float4(x * w.x + bb.x, x * w.y + bb.y,
                        x * w.z + bb.z, x * w.w + bb.w);
        mval = (x != -1.f && x != 0.f) ? 1.f : 0.f;
    }

    const float bv = beta_ws[f * BT + bt];
    const int widx = bt * 64 + f * 16 + c;          // float4 index in [B,T,256]

    ((float4*)(out + OFF_F))[widx] = v;
    ((float4*)(out + OFF_D))[widx] = make_float4(bv, bv, bv, bv);
    ((float4*)(out + OFF_M))[widx] = make_float4(mval, mval, mval, mval);

    // times copy: first BT/4 threads, coalesced float4
    if (u < BT / 4) {
        ((float4*)(out + OFF_T))[u] = ((const float4*)times)[u];
    }
}

extern "C" void kernel_launch(void* const* d_in, const int* in_sizes, int n_in,
                              void* d_out, int out_size, void* d_ws, size_t ws_size,
                              hipStream_t stream) {
    const int*   cat1  = (const int*)d_in[0];
    const int*   cat2  = (const int*)d_in[1];
    const float* num1  = (const float*)d_in[2];
    const float* num2  = (const float*)d_in[3];
    const float* times = (const float*)d_in[4];
    const float* E1    = (const float*)d_in[5];
    const float* E2    = (const float*)d_in[6];
    const float* w1    = (const float*)d_in[7];
    const float* b1    = (const float*)d_in[8];
    const float* w2    = (const float*)d_in[9];
    const float* b2    = (const float*)d_in[10];
    float* out     = (float*)d_out;
    float* beta_ws = (float*)d_ws;   // needs 4*B*T*4 = 2 MB scratch

    beta_scan_kernel<<<BB, 256, 0, stream>>>(cat1, cat2, num1, num2, times, beta_ws);

    const int nthreads = 4 * BT * 16;                // 8388608
    expand_kernel<<<nthreads / 256, 256, 0, stream>>>(
        cat1, cat2, num1, num2, times, E1, E2, w1, b1, w2, b2, beta_ws, out);
}

// Round 3
// 466.026 us; speedup vs baseline: 1.0082x; 1.0082x over previous
//
#include <hip/hip_runtime.h>

// Problem constants (from reference): B=64, T=2048, D=64, V=100000
#define BB 64
#define TT 2048
#define DD 64
#define BT (BB * TT)                 // 131072
#define OFF_F 0                      // features [B,T,256]
#define OFF_T (BT * 256)             // times    [B,T]        = 33554432
#define OFF_D (OFF_T + BT)           // delta    [B,T,256]    = 33685504
#define OFF_M (OFF_D + BT * 256)     // mask     [B,T,256]    = 67239936

// native 4-float vector for nontemporal builtins (float4 is a class -> rejected)
typedef float v4f __attribute__((ext_vector_type(4)));

__device__ __forceinline__ void nt_store4(float* p, float x, float y, float z, float w) {
    v4f v = {x, y, z, w};
    __builtin_nontemporal_store(v, (v4f*)p);
}
__device__ __forceinline__ void nt_store4v(float* p, float4 v) {
    nt_store4(p, v.x, v.y, v.z, v.w);
}

// padded LDS index: +1 gap every 32 elems. lane reads pidx(lane*32+k):
// bank = (lane+k)%32 -> exactly 2 lanes/bank = free on gfx950 (m136).
__device__ __forceinline__ int pidx(int i) { return i + (i >> 5); }

// ---------------------------------------------------------------------------
// Phase 1: beta linear recurrence. One block (single wave, 64 threads) per
// (f, b) sequence -> 256 blocks, all CUs active.
// beta[i] = a_i*beta[i-1] + c_i, a_i = m_{i-1}*pad_i (0/1), c_i = dt_i*pad_i.
// Lane owns 32 contiguous steps; affine-compose + wave scan + replay.
// All arithmetic exact (0/1 multipliers, integer-valued times) -> bitwise
// identical to reference serial scan.
// Output layout: beta_ws[(b*TT+i)*4 + f]  (token-major, float4 per token).
// ---------------------------------------------------------------------------
__global__ __launch_bounds__(64) void beta_scan_kernel(
    const int* __restrict__ cat1, const int* __restrict__ cat2,
    const float* __restrict__ num1, const float* __restrict__ num2,
    const float* __restrict__ times, float* __restrict__ beta_ws)
{
    __shared__ float s_t[2112];
    __shared__ float s_v[2112];
    const int f    = blockIdx.x >> 6;
    const int b    = blockIdx.x & 63;
    const int lane = threadIdx.x;

    // stage times + this feature's values, float4-vectorized
    const float4* tsrc = (const float4*)(times + b * TT);
    for (int i4 = lane; i4 < TT / 4; i4 += 64) {
        float4 t = tsrc[i4];
        int base = i4 * 4;
        s_t[pidx(base + 0)] = t.x;
        s_t[pidx(base + 1)] = t.y;
        s_t[pidx(base + 2)] = t.z;
        s_t[pidx(base + 3)] = t.w;
        float4 v;
        if (f == 0) {
            int4 ci = ((const int4*)(cat1 + b * TT))[i4];
            v = make_float4((float)ci.x, (float)ci.y, (float)ci.z, (float)ci.w);
        } else if (f == 1) {
            int4 ci = ((const int4*)(cat2 + b * TT))[i4];
            v = make_float4((float)ci.x, (float)ci.y, (float)ci.z, (float)ci.w);
        } else if (f == 2) {
            v = ((const float4*)(num1 + b * TT))[i4];
        } else {
            v = ((const float4*)(num2 + b * TT))[i4];
        }
        s_v[pidx(base + 0)] = v.x;
        s_v[pidx(base + 1)] = v.y;
        s_v[pidx(base + 2)] = v.z;
        s_v[pidx(base + 3)] = v.w;
    }
    __syncthreads();

    const int lo = lane * 32;

    // pass 1: compose this lane's 32 affine steps
    float A = 1.f, C = 0.f;
    #pragma unroll
    for (int k = 0; k < 32; ++k) {
        int i = lo + k;
        float a, c;
        if (i == 0) { a = 0.f; c = 0.f; }   // beta[0] = 0
        else {
            float ti  = s_t[pidx(i)];
            float tp  = s_t[pidx(i - 1)];
            float fv  = s_v[pidx(i - 1)];
            float pad = (ti != -1.f) ? 1.f : 0.f;
            float m   = (fv != -1.f && fv != 0.f) ? 1.f : 0.f;
            a = m * pad;
            c = (ti - tp) * pad;
        }
        C = a * C + c;
        A = A * a;
    }
    // inclusive wave scan (affine composition)
    for (int d = 1; d < 64; d <<= 1) {
        float Ap = __shfl_up(A, d);
        float Cp = __shfl_up(C, d);
        if (lane >= d) { C = A * Cp + C; A = A * Ap; }
    }
    float beta = __shfl_up(C, 1);
    if (lane == 0) beta = 0.f;

    // pass 2: replay with true incoming beta, write token-major
    float* out = beta_ws + (size_t)b * TT * 4 + f;
    #pragma unroll
    for (int k = 0; k < 32; ++k) {
        int i = lo + k;
        float a, c;
        if (i == 0) { a = 0.f; c = 0.f; }
        else {
            float ti  = s_t[pidx(i)];
            float tp  = s_t[pidx(i - 1)];
            float fv  = s_v[pidx(i - 1)];
            float pad = (ti != -1.f) ? 1.f : 0.f;
            float m   = (fv != -1.f && fv != 0.f) ? 1.f : 0.f;
            a = m * pad;
            c = (ti - tp) * pad;
        }
        beta = a * beta + c;
        out[i * 4] = beta;
    }
}

// ---------------------------------------------------------------------------
// Phase 2: expansion. One thread per (token bt, float4-chunk c in [0,16)),
// handling ALL 4 features -> branch-free, 2M threads.
// Per thread: 2 embedding float4 gathers + 2 FMA rows + 12 nontemporal
// float4 stores (features/delta/mask). Output bypasses L2 (nt) so L2 stays
// dedicated to the 51 MB embedding tables.
// ---------------------------------------------------------------------------
__global__ __launch_bounds__(256) void expand_kernel(
    const int* __restrict__ cat1, const int* __restrict__ cat2,
    const float* __restrict__ num1, const float* __restrict__ num2,
    const float* __restrict__ times,
    const float* __restrict__ E1, const float* __restrict__ E2,
    const float* __restrict__ w1, const float* __restrict__ b1,
    const float* __restrict__ w2, const float* __restrict__ b2,
    const float* __restrict__ beta_ws, float* __restrict__ out)
{
    const int u  = blockIdx.x * 256 + threadIdx.x;  // [0, BT*16) = [0, 2^21)
    const int bt = u >> 4;
    const int c  = u & 15;

    const int   i1 = cat1[bt];
    const int   i2 = cat2[bt];
    const float x1 = num1[bt];
    const float x2 = num2[bt];

    const float4 e1  = ((const float4*)(E1 + (size_t)i1 * DD))[c];
    const float4 e2  = ((const float4*)(E2 + (size_t)i2 * DD))[c];
    const float4 wc1 = ((const float4*)w1)[c];
    const float4 bc1 = ((const float4*)b1)[c];
    const float4 wc2 = ((const float4*)w2)[c];
    const float4 bc2 = ((const float4*)b2)[c];
    const float4 n1  = make_float4(x1 * wc1.x + bc1.x, x1 * wc1.y + bc1.y,
                                   x1 * wc1.z + bc1.z, x1 * wc1.w + bc1.w);
    const float4 n2  = make_float4(x2 * wc2.x + bc2.x, x2 * wc2.y + bc2.y,
                                   x2 * wc2.z + bc2.z, x2 * wc2.w + bc2.w);

    const float4 bet = ((const float4*)beta_ws)[bt];   // (f0,f1,f2,f3)

    const float m1 = (i1 != -1 && i1 != 0) ? 1.f : 0.f;
    const float m2 = (i2 != -1 && i2 != 0) ? 1.f : 0.f;
    const float m3 = (x1 != -1.f && x1 != 0.f) ? 1.f : 0.f;
    const float m4 = (x2 != -1.f && x2 != 0.f) ? 1.f : 0.f;

    const int base = bt * 64 + c;                      // float4 index, f stride 16
    float* outF = out + OFF_F;
    float* outD = out + OFF_D;
    float* outM = out + OFF_M;

    nt_store4v(outF + 4 * (base),      e1);
    nt_store4v(outF + 4 * (base + 16), e2);
    nt_store4v(outF + 4 * (base + 32), n1);
    nt_store4v(outF + 4 * (base + 48), n2);

    nt_store4(outD + 4 * (base),      bet.x, bet.x, bet.x, bet.x);
    nt_store4(outD + 4 * (base + 16), bet.y, bet.y, bet.y, bet.y);
    nt_store4(outD + 4 * (base + 32), bet.z, bet.z, bet.z, bet.z);
    nt_store4(outD + 4 * (base + 48), bet.w, bet.w, bet.w, bet.w);

    nt_store4(outM + 4 * (base),      m1, m1, m1, m1);
    nt_store4(outM + 4 * (base + 16), m2, m2, m2, m2);
    nt_store4(outM + 4 * (base + 32), m3, m3, m3, m3);
    nt_store4(outM + 4 * (base + 48), m4, m4, m4, m4);

    // times copy: first BT/4 threads, coalesced float4
    if (u < BT / 4) {
        float4 t = ((const float4*)times)[u];
        nt_store4v(out + OFF_T + 4 * u, t);
    }
}

extern "C" void kernel_launch(void* const* d_in, const int* in_sizes, int n_in,
                              void* d_out, int out_size, void* d_ws, size_t ws_size,
                              hipStream_t stream) {
    const int*   cat1  = (const int*)d_in[0];
    const int*   cat2  = (const int*)d_in[1];
    const float* num1  = (const float*)d_in[2];
    const float* num2  = (const float*)d_in[3];
    const float* times = (const float*)d_in[4];
    const float* E1    = (const float*)d_in[5];
    const float* E2    = (const float*)d_in[6];
    const float* w1    = (const float*)d_in[7];
    const float* b1    = (const float*)d_in[8];
    const float* w2    = (const float*)d_in[9];
    const float* b2    = (const float*)d_in[10];
    float* out     = (float*)d_out;
    float* beta_ws = (float*)d_ws;   // 4*B*T*4 = 2 MB scratch, [bt][f] layout

    beta_scan_kernel<<<4 * BB, 64, 0, stream>>>(cat1, cat2, num1, num2, times, beta_ws);

    expand_kernel<<<(BT * 16) / 256, 256, 0, stream>>>(
        cat1, cat2, num1, num2, times, E1, E2, w1, b1, w2, b2, beta_ws, out);
}

// Round 4
// 458.009 us; speedup vs baseline: 1.0258x; 1.0175x over previous
//
#include <hip/hip_runtime.h>

// Problem constants (from reference): B=64, T=2048, D=64, V=100000
#define BB 64
#define TT 2048
#define DD 64
#define BT (BB * TT)                 // 131072
#define OFF_F 0                      // features [B,T,256]
#define OFF_T (BT * 256)             // times    [B,T]        = 33554432
#define OFF_D (OFF_T + BT)           // delta    [B,T,256]    = 33685504
#define OFF_M (OFF_D + BT * 256)     // mask     [B,T,256]    = 67239936

// native 4-float vector for nontemporal builtins (float4 is a class -> rejected)
typedef float v4f __attribute__((ext_vector_type(4)));

__device__ __forceinline__ void nt_store4(float* p, float x, float y, float z, float w) {
    v4f v = {x, y, z, w};
    __builtin_nontemporal_store(v, (v4f*)p);
}
__device__ __forceinline__ void nt_store4v(float* p, float4 v) {
    nt_store4(p, v.x, v.y, v.z, v.w);
}

// ---------------------------------------------------------------------------
// Phase 1: beta linear recurrence. One block = one wave per (f,b) sequence,
// 256 blocks -> 1 block/CU. Fully register-resident: each lane float4-loads
// its 32-step window (t, v) straight from global; no LDS, no barrier.
// beta[i] = a_i*beta[i-1] + c_i, a_i = m_{i-1}*pad_i (0/1), c_i = dt_i*pad_i.
// Exact arithmetic (0/1 multipliers, integer-valued times) -> bitwise equal
// to the reference serial scan.
// Output layout: beta_ws[(b*TT+i)*4 + f]  (token-major float4 per token).
// ---------------------------------------------------------------------------
__global__ __launch_bounds__(64) void beta_scan_kernel(
    const int* __restrict__ cat1, const int* __restrict__ cat2,
    const float* __restrict__ num1, const float* __restrict__ num2,
    const float* __restrict__ times, float* __restrict__ beta_ws)
{
    const int f    = blockIdx.x >> 6;
    const int b    = blockIdx.x & 63;
    const int lane = threadIdx.x;
    const int lo   = lane * 32;

    const float* trow = times + b * TT;

    float t[32], v[32];
    {
        const float4* t4 = (const float4*)(trow + lo);
        #pragma unroll
        for (int q = 0; q < 8; ++q) {
            float4 x = t4[q];
            t[4*q+0] = x.x; t[4*q+1] = x.y; t[4*q+2] = x.z; t[4*q+3] = x.w;
        }
    }
    // wave-uniform branch: f constant per block
    if (f < 2) {
        const int* crow = (f == 0 ? cat1 : cat2) + b * TT;
        const int4* c4 = (const int4*)(crow + lo);
        #pragma unroll
        for (int q = 0; q < 8; ++q) {
            int4 x = c4[q];
            v[4*q+0] = (float)x.x; v[4*q+1] = (float)x.y;
            v[4*q+2] = (float)x.z; v[4*q+3] = (float)x.w;
        }
    } else {
        const float* nrow = (f == 2 ? num1 : num2) + b * TT;
        const float4* n4 = (const float4*)(nrow + lo);
        #pragma unroll
        for (int q = 0; q < 8; ++q) {
            float4 x = n4[q];
            v[4*q+0] = x.x; v[4*q+1] = x.y; v[4*q+2] = x.z; v[4*q+3] = x.w;
        }
    }
    // boundary values for k==0 (lane>0 reads element lo-1)
    float tprev = 0.f, vprev = 0.f;
    if (lane > 0) {
        tprev = trow[lo - 1];
        if      (f == 0) vprev = (float)cat1[b * TT + lo - 1];
        else if (f == 1) vprev = (float)cat2[b * TT + lo - 1];
        else if (f == 2) vprev = num1[b * TT + lo - 1];
        else             vprev = num2[b * TT + lo - 1];
    }

    // pass 1: compose this lane's 32 affine steps
    float A = 1.f, C = 0.f;
    #pragma unroll
    for (int k = 0; k < 32; ++k) {
        float a, c;
        if (lo + k == 0) { a = 0.f; c = 0.f; }          // beta[0] = 0
        else {
            float ti  = t[k];
            float tp  = (k == 0) ? tprev : t[k-1];
            float fv  = (k == 0) ? vprev : v[k-1];
            float pad = (ti != -1.f) ? 1.f : 0.f;
            float m   = (fv != -1.f && fv != 0.f) ? 1.f : 0.f;
            a = m * pad;
            c = (ti - tp) * pad;
        }
        C = a * C + c;
        A = A * a;
    }
    // inclusive wave scan (affine composition)
    for (int d = 1; d < 64; d <<= 1) {
        float Ap = __shfl_up(A, d);
        float Cp = __shfl_up(C, d);
        if (lane >= d) { C = A * Cp + C; A = A * Ap; }
    }
    float beta = __shfl_up(C, 1);
    if (lane == 0) beta = 0.f;

    // pass 2: replay with true incoming beta, write token-major [bt][f]
    float* out = beta_ws + (size_t)b * TT * 4 + f;
    #pragma unroll
    for (int k = 0; k < 32; ++k) {
        float a, c;
        if (lo + k == 0) { a = 0.f; c = 0.f; }
        else {
            float ti  = t[k];
            float tp  = (k == 0) ? tprev : t[k-1];
            float fv  = (k == 0) ? vprev : v[k-1];
            float pad = (ti != -1.f) ? 1.f : 0.f;
            float m   = (fv != -1.f && fv != 0.f) ? 1.f : 0.f;
            a = m * pad;
            c = (ti - tp) * pad;
        }
        beta = a * beta + c;
        out[(lo + k) * 4] = beta;
    }
}

// ---------------------------------------------------------------------------
// Phase 2: expansion. One thread per (token bt, float4-chunk c in [0,16)),
// all 4 features per thread -> branch-free, 2M threads.
// __launch_bounds__(256,8): force <=64 VGPR so 8 waves/SIMD hide the
// dependent cat[bt] -> E[idx] gather latency. 12 nontemporal float4 stores
// (output bypasses L2; L2 stays dedicated to the 51 MB embedding tables).
// ---------------------------------------------------------------------------
__global__ __launch_bounds__(256, 8) void expand_kernel(
    const int* __restrict__ cat1, const int* __restrict__ cat2,
    const float* __restrict__ num1, const float* __restrict__ num2,
    const float* __restrict__ times,
    const float* __restrict__ E1, const float* __restrict__ E2,
    const float* __restrict__ w1, const float* __restrict__ b1,
    const float* __restrict__ w2, const float* __restrict__ b2,
    const float* __restrict__ beta_ws, float* __restrict__ out)
{
    const int u  = blockIdx.x * 256 + threadIdx.x;  // [0, BT*16) = [0, 2^21)
    const int bt = u >> 4;
    const int c  = u & 15;

    const int   i1 = cat1[bt];
    const int   i2 = cat2[bt];
    const float x1 = num1[bt];
    const float x2 = num2[bt];

    const float4 e1  = ((const float4*)(E1 + (size_t)i1 * DD))[c];
    const float4 e2  = ((const float4*)(E2 + (size_t)i2 * DD))[c];
    const float4 wc1 = ((const float4*)w1)[c];
    const float4 bc1 = ((const float4*)b1)[c];
    const float4 wc2 = ((const float4*)w2)[c];
    const float4 bc2 = ((const float4*)b2)[c];
    const float4 n1  = make_float4(x1 * wc1.x + bc1.x, x1 * wc1.y + bc1.y,
                                   x1 * wc1.z + bc1.z, x1 * wc1.w + bc1.w);
    const float4 n2  = make_float4(x2 * wc2.x + bc2.x, x2 * wc2.y + bc2.y,
                                   x2 * wc2.z + bc2.z, x2 * wc2.w + bc2.w);

    const float4 bet = ((const float4*)beta_ws)[bt];   // (f0,f1,f2,f3)

    const float m1 = (i1 != -1 && i1 != 0) ? 1.f : 0.f;
    const float m2 = (i2 != -1 && i2 != 0) ? 1.f : 0.f;
    const float m3 = (x1 != -1.f && x1 != 0.f) ? 1.f : 0.f;
    const float m4 = (x2 != -1.f && x2 != 0.f) ? 1.f : 0.f;

    const int base = bt * 64 + c;                      // float4 index, f stride 16
    float* outF = out + OFF_F;
    float* outD = out + OFF_D;
    float* outM = out + OFF_M;

    nt_store4v(outF + 4 * (base),      e1);
    nt_store4v(outF + 4 * (base + 16), e2);
    nt_store4v(outF + 4 * (base + 32), n1);
    nt_store4v(outF + 4 * (base + 48), n2);

    nt_store4(outD + 4 * (base),      bet.x, bet.x, bet.x, bet.x);
    nt_store4(outD + 4 * (base + 16), bet.y, bet.y, bet.y, bet.y);
    nt_store4(outD + 4 * (base + 32), bet.z, bet.z, bet.z, bet.z);
    nt_store4(outD + 4 * (base + 48), bet.w, bet.w, bet.w, bet.w);

    nt_store4(outM + 4 * (base),      m1, m1, m1, m1);
    nt_store4(outM + 4 * (base + 16), m2, m2, m2, m2);
    nt_store4(outM + 4 * (base + 32), m3, m3, m3, m3);
    nt_store4(outM + 4 * (base + 48), m4, m4, m4, m4);

    // times copy: first BT/4 threads, coalesced float4
    if (u < BT / 4) {
        float4 t = ((const float4*)times)[u];
        nt_store4v(out + OFF_T + 4 * u, t);
    }
}

extern "C" void kernel_launch(void* const* d_in, const int* in_sizes, int n_in,
                              void* d_out, int out_size, void* d_ws, size_t ws_size,
                              hipStream_t stream) {
    const int*   cat1  = (const int*)d_in[0];
    const int*   cat2  = (const int*)d_in[1];
    const float* num1  = (const float*)d_in[2];
    const float* num2  = (const float*)d_in[3];
    const float* times = (const float*)d_in[4];
    const float* E1    = (const float*)d_in[5];
    const float* E2    = (const float*)d_in[6];
    const float* w1    = (const float*)d_in[7];
    const float* b1    = (const float*)d_in[8];
    const float* w2    = (const float*)d_in[9];
    const float* b2    = (const float*)d_in[10];
    float* out     = (float*)d_out;
    float* beta_ws = (float*)d_ws;   // 4*B*T*4 = 2 MB scratch, [bt][f] layout

    beta_scan_kernel<<<4 * BB, 64, 0, stream>>>(cat1, cat2, num1, num2, times, beta_ws);

    expand_kernel<<<(BT * 16) / 256, 256, 0, stream>>>(
        cat1, cat2, num1, num2, times, E1, E2, w1, b1, w2, b2, beta_ws, out);
}